// Round 19
// baseline (116.609 us; speedup 1.0000x reference)
//
#include <hip/hip_runtime.h>
#include <math.h>

#define BATCH 2
#define SEQ   4096
#define DIM   512
#define HEADS 8
#define DH    64

typedef _Float16 f16;
typedef __attribute__((ext_vector_type(8)))  _Float16 f16x8;
typedef __attribute__((ext_vector_type(4)))  _Float16 f16x4;
typedef __attribute__((ext_vector_type(2)))  __fp16   h16x2;
typedef __attribute__((ext_vector_type(4)))  float f32x4;
typedef __attribute__((ext_vector_type(16))) float f32x16;

// raw v_exp_f32 (= exp2, ~1 ulp); inputs bounded (|S| <~ 12)
__device__ __forceinline__ float exp2_raw(float x) {
    float r;
    asm("v_exp_f32 %0, %1" : "=v"(r) : "v"(x));
    return r;
}

__device__ __forceinline__ void gload_lds16(const void* g, void* l) {
  __builtin_amdgcn_global_load_lds(
      (const __attribute__((address_space(1))) unsigned int*)g,
      (__attribute__((address_space(3))) unsigned int*)l, 16, 0, 0);
}

// pack 2 f32 -> 2 f16 (RTZ), one v_cvt_pkrtz_f16_f32
__device__ __forceinline__ unsigned pk2(float a, float b) {
    h16x2 h = __builtin_amdgcn_cvt_pkrtz(a, b);
    union { h16x2 h; unsigned u; } c; c.h = h; return c.u;
}
// v_permlane32_swap_b32: swaps lane halves between the two operands
__device__ __forceinline__ void pl32swap(unsigned &a, unsigned &b) {
    asm volatile("v_permlane32_swap_b32 %0, %1" : "+v"(a), "+v"(b));
}
// acc += sum of the 2 f16 in word w (f32 accumulate)
__device__ __forceinline__ float dot2acc(unsigned w, float acc) {
#if __has_builtin(__builtin_amdgcn_fdot2)
    union { unsigned u; h16x2 h; } c; c.u = w;
    h16x2 one = {(__fp16)1.0f, (__fp16)1.0f};
    return __builtin_amdgcn_fdot2(c.h, one, acc, false);
#else
    union { unsigned u; __fp16 h[2]; } c; c.u = w;
    return acc + (float)c.h[0] + (float)c.h[1];
#endif
}

// ---------------------------------------------------------------------------
// Kernel 0: convert x (4194304), w_qkv (786432), w_out (262144) to f16.
// ---------------------------------------------------------------------------
__global__ __launch_bounds__(256) void prep_kernel(
    const float* __restrict__ x, const float* __restrict__ wqkv,
    const float* __restrict__ wout,
    f16* __restrict__ xh, f16* __restrict__ wqh, f16* __restrict__ woh)
{
    int i4 = (blockIdx.x * 256 + threadIdx.x) * 4;
    const float* src; f16* dh; int idx;
    if (i4 < 4194304)      { src = x;    dh = xh;  idx = i4; }
    else if (i4 < 4980736) { src = wqkv; dh = wqh; idx = i4 - 4194304; }
    else                   { src = wout; dh = woh; idx = i4 - 4980736; }
    float4 v = *(const float4*)(src + idx);
    f16x4 h;
    h[0] = (f16)v.x; h[1] = (f16)v.y; h[2] = (f16)v.z; h[3] = (f16)v.w;
    *(f16x4*)(dh + idx) = h;
}

// ---------------------------------------------------------------------------
// Kernel 1: QKV projection, 1-pass f16 MFMA, BN=128 tile, dbuf K-loop
// (drain-0 sync).  Q scaled by 0.125*log2(e).  Outputs:
//   q [bh][s][d]; k fragment-major K' (r13); v fragment-major V' (r15).
// ---------------------------------------------------------------------------
__global__ __launch_bounds__(256) void qkv_mfma_kernel(
    const f16* __restrict__ xh_, const f16* __restrict__ wh,
    f16* __restrict__ qh, f16* __restrict__ kh, f16* __restrict__ vth)
{
    __shared__ __align__(16) char smem[49152];
    // dbuf d: d*24576 + {Xh 8K @0, Wh 16K @8192}
    const int t = threadIdx.x, lane = t & 63, wave = t >> 6;
    const int l15 = lane & 15, l4 = lane >> 4;
    const int m0 = blockIdx.x * 64;
    const int n0 = blockIdx.y * 128;          // [0, 1536)
    const int which = n0 >> 9;                // 0=q,1=k,2=v
    const int hbase = (n0 & 511) >> 6;        // first head of this 128-tile

    const int xr0 = t >> 3,         xc0 = (t & 7) ^ (xr0 & 7);
    const int xr1 = (t + 256) >> 3, xc1 = ((t + 256) & 7) ^ (xr1 & 7);

#define STAGEQ(k0, dbase)                                                     \
    do {                                                                      \
        gload_lds16(xh_ + (size_t)(m0 + xr0) * DIM + (k0) + xc0 * 8,          \
                    smem + (dbase) + t * 16);                                 \
        gload_lds16(xh_ + (size_t)(m0 + xr1) * DIM + (k0) + xc1 * 8,          \
                    smem + (dbase) + (t + 256) * 16);                         \
        _Pragma("unroll")                                                     \
        for (int it_ = 0; it_ < 4; ++it_) {                                   \
            int p_ = t + it_ * 256;                                           \
            int wr_ = p_ >> 3, wc_ = (p_ & 7) ^ (wr_ & 7);                    \
            gload_lds16(wh + (size_t)(n0 + wr_) * DIM + (k0) + wc_ * 8,       \
                        smem + (dbase) + 8192 + p_ * 16);                     \
        }                                                                     \
    } while (0)

    f32x4 acc[8];
#pragma unroll
    for (int nb = 0; nb < 8; ++nb) acc[nb] = (f32x4){0.f, 0.f, 0.f, 0.f};

    STAGEQ(0, 0);
    __syncthreads();

    for (int ks = 0; ks < 8; ++ks) {
        const int cur = ks & 1;
        if (ks < 7) STAGEQ((ks + 1) * 64, (cur ^ 1) * 24576);
        const char* bX = smem + cur * 24576;
        const char* bW = bX + 8192;

        f16x8 ah[2];
        const int arow = wave * 16 + l15;
#pragma unroll
        for (int kb = 0; kb < 2; ++kb) {
            int ac = (l4 + 4 * kb) ^ (arow & 7);
            ah[kb] = *(const f16x8*)(bX + arow * 128 + ac * 16);
        }
#pragma unroll
        for (int nb = 0; nb < 8; ++nb) {
            const int brow = nb * 16 + l15;
#pragma unroll
            for (int kb = 0; kb < 2; ++kb) {
                int bc = (l4 + 4 * kb) ^ (brow & 7);
                f16x8 b_h = *(const f16x8*)(bW + brow * 128 + bc * 16);
                acc[nb] = __builtin_amdgcn_mfma_f32_16x16x32_f16(ah[kb], b_h, acc[nb], 0, 0, 0);
            }
        }
        __syncthreads();   // drains prefetch + all LDS reads of buf[cur]
    }

    if (which == 0) {
        const float qscale = 0.125f * 1.44269504f;
#pragma unroll
        for (int nb = 0; nb < 8; ++nb) {
            int h = hbase + (nb >> 2);
            int d = (nb & 3) * 16 + l15;
#pragma unroll
            for (int r = 0; r < 4; ++r) {
                int m  = m0 + wave * 16 + l4 * 4 + r;
                int b_ = m >> 12, s = m & (SEQ - 1);
                qh[((size_t)((b_ * HEADS + h) * SEQ + s)) * DH + d] =
                    (f16)(acc[nb][r] * qscale);
            }
        }
    } else if (which == 1) {
        // fragment-major K' (verified r13), per-nb head
        const int tile = (m0 & (SEQ - 1)) >> 6;
        const int b_   = m0 >> 12;
        const int jb   = wave >> 1;
        const int h5w  = l15 >> 3, jj = l15 & 7;
#pragma unroll
        for (int nb = 0; nb < 8; ++nb) {
            int h  = hbase + (nb >> 2);
            int bh = b_ * HEADS + h;
            f16* kb = kh + (size_t)bh * SEQ * DH + (size_t)tile * 4096;
            int ksn = nb & 3;
#pragma unroll
            for (int r = 0; r < 4; ++r) {
                int q31 = (wave & 1) * 16 + l4 * 4 + r;
                kb[(jb * 4 + ksn) * 512 + (h5w * 32 + q31) * 8 + jj] =
                    (f16)acc[nb][r];
            }
        }
    } else {
        // fragment-major V' (verified r15), per-nb head
        const int tile = (m0 & (SEQ - 1)) >> 6;
        const int b_   = m0 >> 12;
        const int h5p  = l4 >> 1;
        const int j0   = (l4 * 4) & 7;
#pragma unroll
        for (int nb = 0; nb < 8; ++nb) {
            int h  = hbase + (nb >> 2);
            int bh = b_ * HEADS + h;
            f16* vb = vth + (size_t)bh * SEQ * DH + (size_t)tile * 4096;
            int nbh = nb & 3;
            f16x4 v;
#pragma unroll
            for (int r = 0; r < 4; ++r) v[r] = (f16)acc[nb][r];
            int off = ((nbh >> 1) * 4 + wave) * 512 +
                      (h5p * 32 + (nbh & 1) * 16 + l15) * 8 + j0;
            *(f16x4*)(vb + off) = v;
        }
    }
#undef STAGEQ
}

// ---------------------------------------------------------------------------
// Kernel 2: flash attention (r16 structure + ILP): f16 32x32x16, swapped
// QK^T, fixed-base exp2 softmax, P via permlane.  K/V fragment-major in LDS.
// ILP: persistent zero C for QK^T (no per-iter acc zeroing); PV accumulator
// split into even/odd-ks chains (4 parallel MFMA streams), merged once.
// Double-buffered, drain-0 sync.  8 waves, KV-split-2, plain-sum merge.
// ---------------------------------------------------------------------------
__global__ __launch_bounds__(512, 4) void attn_mfma_kernel(
    const f16* __restrict__ qh_,
    const f16* __restrict__ kh_, const f16* __restrict__ vth_,
    f16* __restrict__ o_h)
{
    __shared__ __align__(16) char smem[65536];
    // staging dbuf d: d*32768 + {K_A@0, V_A@8192, K_B@16384, V_B@24576}
    // merge (reused):  [0 .. 36864)   4 waves x 64 lanes x 144B
    // epilogue (reused): 36864 + wave*4096 (A waves only)
    const int t = threadIdx.x, lane = t & 63, wave = t >> 6;
    const int q31 = lane & 31, h5 = lane >> 5;
    const int grp = wave >> 2, w4 = wave & 3;
    const int bid  = blockIdx.x;
    const int flat = (bid & 7) * 64 + (bid >> 3);   // XCD swizzle (512 = 8*64)
    const int qt = flat & 31, bh = flat >> 5;
    const int q0 = qt * 128;

    const f16* kgb = kh_  + (size_t)bh * SEQ * DH;   // K' fragment-major
    const f16* vgb = vth_ + (size_t)bh * SEQ * DH;   // V' fragment-major

#define STAGE(s2, dbase)                                                      \
    do {                                                                      \
        gload_lds16(kgb + (size_t)(2 * (s2)) * 4096 + t * 8,                  \
                    smem + (dbase) + t * 16);                                 \
        gload_lds16(vgb + (size_t)(2 * (s2)) * 4096 + t * 8,                  \
                    smem + (dbase) + 8192 + t * 16);                          \
        gload_lds16(kgb + (size_t)(2 * (s2) + 1) * 4096 + t * 8,              \
                    smem + (dbase) + 16384 + t * 16);                         \
        gload_lds16(vgb + (size_t)(2 * (s2) + 1) * 4096 + t * 8,              \
                    smem + (dbase) + 24576 + t * 16);                         \
    } while (0)

    // Q fragments (B-operand): lane q=q31, k = h5*8 + ks*16 + j
    f16x8 qfh[4];
    {
        const int qrow = q0 + w4 * 32 + q31;
        size_t base = ((size_t)bh * SEQ + qrow) * DH + h5 * 8;
#pragma unroll
        for (int ks = 0; ks < 4; ++ks)
            qfh[ks] = *(const f16x8*)(qh_ + base + ks * 16);
    }

    // persistent zero C operand (no per-iter accumulator zeroing)
    f32x16 z16;
#pragma unroll
    for (int r = 0; r < 16; ++r) z16[r] = 0.f;

    // PV accumulators: even/odd-ks chains (4 parallel MFMA streams)
    f32x16 o_e[2], o_o[2];
#pragma unroll
    for (int dt = 0; dt < 2; ++dt)
#pragma unroll
        for (int r = 0; r < 16; ++r) { o_e[dt][r] = 0.f; o_o[dt][r] = 0.f; }
    float run_l = 0.f;

    STAGE(0, 0);
    __syncthreads();

    const int NT = SEQ / 128;   // 32
    for (int s = 0; s < NT; ++s) {
        const int cur = s & 1;
        if (s + 1 < NT) STAGE(s + 1, (cur ^ 1) * 32768);
        const char* bK = smem + cur * 32768 + grp * 16384;
        const char* bV = bK + 8192;

        // --- S^T = K Q^T : conflict-free linear fragment reads; C=z16
        f32x16 sacc[2];
        __builtin_amdgcn_s_setprio(1);
#pragma unroll
        for (int jb = 0; jb < 2; ++jb) {
            f16x8 kf0 = *(const f16x8*)(bK + (jb * 4 + 0) * 1024 + lane * 16);
            f32x16 a = __builtin_amdgcn_mfma_f32_32x32x16_f16(kf0, qfh[0], z16, 0, 0, 0);
#pragma unroll
            for (int ks = 1; ks < 4; ++ks) {
                f16x8 kf = *(const f16x8*)(bK + (jb * 4 + ks) * 1024 + lane * 16);
                a = __builtin_amdgcn_mfma_f32_32x32x16_f16(kf, qfh[ks], a, 0, 0, 0);
            }
            sacc[jb] = a;
        }
        __builtin_amdgcn_s_setprio(0);

        // --- P = exp2(S), pack to f16; row-sum via dot2 (consistent l)
        float ls0 = 0.f, ls1 = 0.f, ls2 = 0.f, ls3 = 0.f;
        unsigned pw[2][8];
#pragma unroll
        for (int jb = 0; jb < 2; ++jb)
#pragma unroll
            for (int k = 0; k < 8; ++k) {
                float p0 = exp2_raw(sacc[jb][2 * k]);
                float p1 = exp2_raw(sacc[jb][2 * k + 1]);
                pw[jb][k] = pk2(p0, p1);
                switch (k & 3) {
                    case 0: ls0 = dot2acc(pw[jb][k], ls0); break;
                    case 1: ls1 = dot2acc(pw[jb][k], ls1); break;
                    case 2: ls2 = dot2acc(pw[jb][k], ls2); break;
                    default: ls3 = dot2acc(pw[jb][k], ls3); break;
                }
            }
        float ls = (ls0 + ls1) + (ls2 + ls3);
        ls += __shfl_xor(ls, 32);
        run_l += ls;

        // --- O^T += Vt P^T : even/odd ks feed separate accumulator chains
        __builtin_amdgcn_s_setprio(1);
#pragma unroll
        for (int ks = 0; ks < 4; ++ks) {
            const int jb = ks >> 1, c = (ks & 1) * 4;
            unsigned y0a = pw[jb][c + 0];
            unsigned y0b = pw[jb][c + 1];
            unsigned y1a = pw[jb][c + 2];
            unsigned y1b = pw[jb][c + 3];
            pl32swap(y0a, y1a);   // y0a=B word0, y1a=B word2
            pl32swap(y0b, y1b);   // y0b=B word1, y1b=B word3
            union { f16x8 v; unsigned u[4]; } bb;
            bb.u[0] = y0a; bb.u[1] = y0b; bb.u[2] = y1a; bb.u[3] = y1b;
            if ((ks & 1) == 0) {
#pragma unroll
                for (int dt = 0; dt < 2; ++dt) {
                    f16x8 vb = *(const f16x8*)(bV + (dt * 4 + ks) * 1024 + lane * 16);
                    o_e[dt] = __builtin_amdgcn_mfma_f32_32x32x16_f16(vb, bb.v, o_e[dt], 0, 0, 0);
                }
            } else {
#pragma unroll
                for (int dt = 0; dt < 2; ++dt) {
                    f16x8 vb = *(const f16x8*)(bV + (dt * 4 + ks) * 1024 + lane * 16);
                    o_o[dt] = __builtin_amdgcn_mfma_f32_32x32x16_f16(vb, bb.v, o_o[dt], 0, 0, 0);
                }
            }
        }
        __builtin_amdgcn_s_setprio(0);

        __syncthreads();   // drains prefetch + all LDS reads of buf[cur]
    }

    // combine even/odd chains
    f32x16 o_acc[2];
#pragma unroll
    for (int dt = 0; dt < 2; ++dt)
#pragma unroll
        for (int r = 0; r < 16; ++r) o_acc[dt][r] = o_e[dt][r] + o_o[dt][r];

    // --- merge B partials into A (plain sum: same exp2 base), epilogue by A
    if (grp == 1) {
        float* mb = (float*)(smem + w4 * 9216 + lane * 144);
#pragma unroll
        for (int dt = 0; dt < 2; ++dt)
#pragma unroll
            for (int rr = 0; rr < 4; ++rr) {
                float4 v4 = {o_acc[dt][rr*4+0], o_acc[dt][rr*4+1],
                             o_acc[dt][rr*4+2], o_acc[dt][rr*4+3]};
                *(float4*)(mb + dt * 16 + rr * 4) = v4;
            }
        mb[32] = run_l;
    }
    __syncthreads();
    if (grp == 0) {
        const float* mb = (const float*)(smem + wave * 9216 + lane * 144);
        float invl = 1.0f / (run_l + mb[32]);

        char* ep = smem + 36864 + wave * 4096;   // [32 q][64 d] f16, swizzled
#pragma unroll
        for (int dt = 0; dt < 2; ++dt)
#pragma unroll
            for (int rr = 0; rr < 4; ++rr) {
                float4 vB = *(const float4*)(mb + dt * 16 + rr * 4);
                f16x4 ov;
                ov[0] = (f16)((o_acc[dt][rr*4+0] + vB.x) * invl);
                ov[1] = (f16)((o_acc[dt][rr*4+1] + vB.y) * invl);
                ov[2] = (f16)((o_acc[dt][rr*4+2] + vB.z) * invl);
                ov[3] = (f16)((o_acc[dt][rr*4+3] + vB.w) * invl);
                int g = rr + 4 * dt;
                *(f16x4*)(ep + q31 * 128 + ((g ^ (q31 & 7)) * 16) + 8 * h5) = ov;
            }
        const int b_ = bh >> 3, hh = bh & 7;
#pragma unroll
        for (int itc = 0; itc < 4; ++itc) {
            int ch = lane + itc * 64;
            int row = ch >> 3, g = ch & 7;
            f16x8 v = *(const f16x8*)(ep + row * 128 + ((g ^ (row & 7)) * 16));
            int s = q0 + wave * 32 + row;
            *(f16x8*)(o_h + ((size_t)(b_ * SEQ + s)) * DIM + hh * DH + g * 8) = v;
        }
    }
#undef STAGE
}

// ---------------------------------------------------------------------------
// Kernel 3: output projection, 1-pass f16 MFMA + bias, BN=128, dbuf K-loop.
// ---------------------------------------------------------------------------
__global__ __launch_bounds__(256) void oproj_mfma_kernel(
    const f16* __restrict__ oh, const f16* __restrict__ wh,
    const float* __restrict__ bias, float* __restrict__ out)
{
    __shared__ __align__(16) char smem[49152];
    // dbuf d: d*24576 + {Oh 8K @0, Wh 16K @8192}
    const int t = threadIdx.x, lane = t & 63, wave = t >> 6;
    const int l15 = lane & 15, l4 = lane >> 4;
    const int m0 = blockIdx.x * 64;
    const int n0 = blockIdx.y * 128;

    const int r0 = t >> 3,         c0 = (t & 7) ^ (r0 & 7);
    const int r1 = (t + 256) >> 3, c1 = ((t + 256) & 7) ^ (r1 & 7);

#define STAGEO(k0, dbase)                                                     \
    do {                                                                      \
        gload_lds16(oh + (size_t)(m0 + r0) * DIM + (k0) + c0 * 8,             \
                    smem + (dbase) + t * 16);                                 \
        gload_lds16(oh + (size_t)(m0 + r1) * DIM + (k0) + c1 * 8,             \
                    smem + (dbase) + (t + 256) * 16);                         \
        _Pragma("unroll")                                                     \
        for (int it_ = 0; it_ < 4; ++it_) {                                   \
            int p_ = t + it_ * 256;                                           \
            int wr_ = p_ >> 3, wc_ = (p_ & 7) ^ (wr_ & 7);                    \
            gload_lds16(wh + (size_t)(n0 + wr_) * DIM + (k0) + wc_ * 8,       \
                        smem + (dbase) + 8192 + p_ * 16);                     \
        }                                                                     \
    } while (0)

    f32x4 acc[8];
#pragma unroll
    for (int nb = 0; nb < 8; ++nb) acc[nb] = (f32x4){0.f, 0.f, 0.f, 0.f};

    STAGEO(0, 0);
    __syncthreads();

    for (int ks = 0; ks < 8; ++ks) {
        const int cur = ks & 1;
        if (ks < 7) STAGEO((ks + 1) * 64, (cur ^ 1) * 24576);
        const char* bO = smem + cur * 24576;
        const char* bW = bO + 8192;

        f16x8 ah[2];
        const int arow = wave * 16 + l15;
#pragma unroll
        for (int kb = 0; kb < 2; ++kb) {
            int ac = (l4 + 4 * kb) ^ (arow & 7);
            ah[kb] = *(const f16x8*)(bO + arow * 128 + ac * 16);
        }
#pragma unroll
        for (int nb = 0; nb < 8; ++nb) {
            const int brow = nb * 16 + l15;
#pragma unroll
            for (int kb = 0; kb < 2; ++kb) {
                int bc = (l4 + 4 * kb) ^ (brow & 7);
                f16x8 b_h = *(const f16x8*)(bW + brow * 128 + bc * 16);
                acc[nb] = __builtin_amdgcn_mfma_f32_16x16x32_f16(ah[kb], b_h, acc[nb], 0, 0, 0);
            }
        }
        __syncthreads();
    }

#pragma unroll
    for (int nb = 0; nb < 8; ++nb) {
        int n = n0 + nb * 16 + l15;
        float bz = bias[n];
#pragma unroll
        for (int r = 0; r < 4; ++r) {
            int m = m0 + wave * 16 + l4 * 4 + r;
            out[(size_t)m * DIM + n] = acc[nb][r] + bz;
        }
    }
#undef STAGEO
}

// ---------------------------------------------------------------------------
extern "C" void kernel_launch(void* const* d_in, const int* in_sizes, int n_in,
                              void* d_out, int out_size, void* d_ws, size_t ws_size,
                              hipStream_t stream) {
    const float* x     = (const float*)d_in[0];
    const float* w_qkv = (const float*)d_in[1];
    const float* w_out = (const float*)d_in[2];
    const float* b_out = (const float*)d_in[3];
    float* out = (float*)d_out;

    const size_t per = (size_t)BATCH * HEADS * SEQ * DH;   // 4194304
    f16* base = (f16*)d_ws;
    f16* xh  = base;                 // 4194304
    f16* wqh = xh + per;             // 786432
    f16* woh = wqh + 786432;         // 262144
    f16* qh  = woh + 262144;
    f16* kh  = qh + per;
    f16* vth = kh + per;
    f16* o_h = vth + per;            // total ~44 MB

    prep_kernel<<<5120, 256, 0, stream>>>(x, w_qkv, w_out, xh, wqh, woh);
    qkv_mfma_kernel<<<dim3(128, 12), 256, 0, stream>>>(xh, wqh, qh, kh, vth);
    attn_mfma_kernel<<<512, 512, 0, stream>>>(qh, kh, vth, o_h);
    oproj_mfma_kernel<<<dim3(128, 4), 256, 0, stream>>>(o_h, woh, b_out, out);
}

// Round 20
// 112.811 us; speedup vs baseline: 1.0337x; 1.0337x over previous
//
#include <hip/hip_runtime.h>
#include <math.h>

#define BATCH 2
#define SEQ   4096
#define DIM   512
#define HEADS 8
#define DH    64

typedef _Float16 f16;
typedef __attribute__((ext_vector_type(8)))  _Float16 f16x8;
typedef __attribute__((ext_vector_type(4)))  _Float16 f16x4;
typedef __attribute__((ext_vector_type(2)))  __fp16   h16x2;
typedef __attribute__((ext_vector_type(4)))  float f32x4;
typedef __attribute__((ext_vector_type(16))) float f32x16;

// raw v_exp_f32 (= exp2, ~1 ulp); inputs bounded (|S| <~ 12)
__device__ __forceinline__ float exp2_raw(float x) {
    float r;
    asm("v_exp_f32 %0, %1" : "=v"(r) : "v"(x));
    return r;
}

__device__ __forceinline__ void gload_lds16(const void* g, void* l) {
  __builtin_amdgcn_global_load_lds(
      (const __attribute__((address_space(1))) unsigned int*)g,
      (__attribute__((address_space(3))) unsigned int*)l, 16, 0, 0);
}

// pack 2 f32 -> 2 f16 (RTZ), one v_cvt_pkrtz_f16_f32
__device__ __forceinline__ unsigned pk2(float a, float b) {
    h16x2 h = __builtin_amdgcn_cvt_pkrtz(a, b);
    union { h16x2 h; unsigned u; } c; c.h = h; return c.u;
}
// v_permlane32_swap_b32: swaps lane halves between the two operands
__device__ __forceinline__ void pl32swap(unsigned &a, unsigned &b) {
    asm volatile("v_permlane32_swap_b32 %0, %1" : "+v"(a), "+v"(b));
}
// acc += sum of the 2 f16 in word w (f32 accumulate)
__device__ __forceinline__ float dot2acc(unsigned w, float acc) {
#if __has_builtin(__builtin_amdgcn_fdot2)
    union { unsigned u; h16x2 h; } c; c.u = w;
    h16x2 one = {(__fp16)1.0f, (__fp16)1.0f};
    return __builtin_amdgcn_fdot2(c.h, one, acc, false);
#else
    union { unsigned u; __fp16 h[2]; } c; c.u = w;
    return acc + (float)c.h[0] + (float)c.h[1];
#endif
}

// ---------------------------------------------------------------------------
// Kernel 0: convert x (4194304), w_qkv (786432), w_out (262144) to f16.
// ---------------------------------------------------------------------------
__global__ __launch_bounds__(256) void prep_kernel(
    const float* __restrict__ x, const float* __restrict__ wqkv,
    const float* __restrict__ wout,
    f16* __restrict__ xh, f16* __restrict__ wqh, f16* __restrict__ woh)
{
    int i4 = (blockIdx.x * 256 + threadIdx.x) * 4;
    const float* src; f16* dh; int idx;
    if (i4 < 4194304)      { src = x;    dh = xh;  idx = i4; }
    else if (i4 < 4980736) { src = wqkv; dh = wqh; idx = i4 - 4194304; }
    else                   { src = wout; dh = woh; idx = i4 - 4980736; }
    float4 v = *(const float4*)(src + idx);
    f16x4 h;
    h[0] = (f16)v.x; h[1] = (f16)v.y; h[2] = (f16)v.z; h[3] = (f16)v.w;
    *(f16x4*)(dh + idx) = h;
}

// ---------------------------------------------------------------------------
// Kernel 1: QKV projection, 1-pass f16 MFMA, BN=128 tile, dbuf K-loop
// (drain-0 sync).  Q scaled by 0.125*log2(e).  Outputs:
//   q [bh][s][d]; k fragment-major K' (r13); v fragment-major V' (r15).
// ---------------------------------------------------------------------------
__global__ __launch_bounds__(256) void qkv_mfma_kernel(
    const f16* __restrict__ xh_, const f16* __restrict__ wh,
    f16* __restrict__ qh, f16* __restrict__ kh, f16* __restrict__ vth)
{
    __shared__ __align__(16) char smem[49152];
    // dbuf d: d*24576 + {Xh 8K @0, Wh 16K @8192}
    const int t = threadIdx.x, lane = t & 63, wave = t >> 6;
    const int l15 = lane & 15, l4 = lane >> 4;
    const int m0 = blockIdx.x * 64;
    const int n0 = blockIdx.y * 128;          // [0, 1536)
    const int which = n0 >> 9;                // 0=q,1=k,2=v
    const int hbase = (n0 & 511) >> 6;        // first head of this 128-tile

    const int xr0 = t >> 3,         xc0 = (t & 7) ^ (xr0 & 7);
    const int xr1 = (t + 256) >> 3, xc1 = ((t + 256) & 7) ^ (xr1 & 7);

#define STAGEQ(k0, dbase)                                                     \
    do {                                                                      \
        gload_lds16(xh_ + (size_t)(m0 + xr0) * DIM + (k0) + xc0 * 8,          \
                    smem + (dbase) + t * 16);                                 \
        gload_lds16(xh_ + (size_t)(m0 + xr1) * DIM + (k0) + xc1 * 8,          \
                    smem + (dbase) + (t + 256) * 16);                         \
        _Pragma("unroll")                                                     \
        for (int it_ = 0; it_ < 4; ++it_) {                                   \
            int p_ = t + it_ * 256;                                           \
            int wr_ = p_ >> 3, wc_ = (p_ & 7) ^ (wr_ & 7);                    \
            gload_lds16(wh + (size_t)(n0 + wr_) * DIM + (k0) + wc_ * 8,       \
                        smem + (dbase) + 8192 + p_ * 16);                     \
        }                                                                     \
    } while (0)

    f32x4 acc[8];
#pragma unroll
    for (int nb = 0; nb < 8; ++nb) acc[nb] = (f32x4){0.f, 0.f, 0.f, 0.f};

    STAGEQ(0, 0);
    __syncthreads();

    for (int ks = 0; ks < 8; ++ks) {
        const int cur = ks & 1;
        if (ks < 7) STAGEQ((ks + 1) * 64, (cur ^ 1) * 24576);
        const char* bX = smem + cur * 24576;
        const char* bW = bX + 8192;

        f16x8 ah[2];
        const int arow = wave * 16 + l15;
#pragma unroll
        for (int kb = 0; kb < 2; ++kb) {
            int ac = (l4 + 4 * kb) ^ (arow & 7);
            ah[kb] = *(const f16x8*)(bX + arow * 128 + ac * 16);
        }
#pragma unroll
        for (int nb = 0; nb < 8; ++nb) {
            const int brow = nb * 16 + l15;
#pragma unroll
            for (int kb = 0; kb < 2; ++kb) {
                int bc = (l4 + 4 * kb) ^ (brow & 7);
                f16x8 b_h = *(const f16x8*)(bW + brow * 128 + bc * 16);
                acc[nb] = __builtin_amdgcn_mfma_f32_16x16x32_f16(ah[kb], b_h, acc[nb], 0, 0, 0);
            }
        }
        __syncthreads();   // drains prefetch + all LDS reads of buf[cur]
    }

    if (which == 0) {
        const float qscale = 0.125f * 1.44269504f;
#pragma unroll
        for (int nb = 0; nb < 8; ++nb) {
            int h = hbase + (nb >> 2);
            int d = (nb & 3) * 16 + l15;
#pragma unroll
            for (int r = 0; r < 4; ++r) {
                int m  = m0 + wave * 16 + l4 * 4 + r;
                int b_ = m >> 12, s = m & (SEQ - 1);
                qh[((size_t)((b_ * HEADS + h) * SEQ + s)) * DH + d] =
                    (f16)(acc[nb][r] * qscale);
            }
        }
    } else if (which == 1) {
        // fragment-major K' (verified r13), per-nb head
        const int tile = (m0 & (SEQ - 1)) >> 6;
        const int b_   = m0 >> 12;
        const int jb   = wave >> 1;
        const int h5w  = l15 >> 3, jj = l15 & 7;
#pragma unroll
        for (int nb = 0; nb < 8; ++nb) {
            int h  = hbase + (nb >> 2);
            int bh = b_ * HEADS + h;
            f16* kb = kh + (size_t)bh * SEQ * DH + (size_t)tile * 4096;
            int ksn = nb & 3;
#pragma unroll
            for (int r = 0; r < 4; ++r) {
                int q31 = (wave & 1) * 16 + l4 * 4 + r;
                kb[(jb * 4 + ksn) * 512 + (h5w * 32 + q31) * 8 + jj] =
                    (f16)acc[nb][r];
            }
        }
    } else {
        // fragment-major V' (verified r15), per-nb head
        const int tile = (m0 & (SEQ - 1)) >> 6;
        const int b_   = m0 >> 12;
        const int h5p  = l4 >> 1;
        const int j0   = (l4 * 4) & 7;
#pragma unroll
        for (int nb = 0; nb < 8; ++nb) {
            int h  = hbase + (nb >> 2);
            int bh = b_ * HEADS + h;
            f16* vb = vth + (size_t)bh * SEQ * DH + (size_t)tile * 4096;
            int nbh = nb & 3;
            f16x4 v;
#pragma unroll
            for (int r = 0; r < 4; ++r) v[r] = (f16)acc[nb][r];
            int off = ((nbh >> 1) * 4 + wave) * 512 +
                      (h5p * 32 + (nbh & 1) * 16 + l15) * 8 + j0;
            *(f16x4*)(vb + off) = v;
        }
    }
#undef STAGEQ
}

// ---------------------------------------------------------------------------
// Kernel 2: flash attention (r16 verified, 81.5us): f16 32x32x16, swapped
// QK^T, fixed-base exp2 softmax (raw v_exp_f32), P via permlane.  K/V
// fragment-major in LDS (linear staging, conflict-free lane*16 reads).
// Double-buffered, drain-0 sync.  8 waves, KV-split-2, plain-sum merge.
// ---------------------------------------------------------------------------
__global__ __launch_bounds__(512, 4) void attn_mfma_kernel(
    const f16* __restrict__ qh_,
    const f16* __restrict__ kh_, const f16* __restrict__ vth_,
    f16* __restrict__ o_h)
{
    __shared__ __align__(16) char smem[65536];
    // staging dbuf d: d*32768 + {K_A@0, V_A@8192, K_B@16384, V_B@24576}
    // merge (reused):  [0 .. 36864)   4 waves x 64 lanes x 144B
    // epilogue (reused): 36864 + wave*4096 (A waves only)
    const int t = threadIdx.x, lane = t & 63, wave = t >> 6;
    const int q31 = lane & 31, h5 = lane >> 5;
    const int grp = wave >> 2, w4 = wave & 3;
    const int bid  = blockIdx.x;
    const int flat = (bid & 7) * 64 + (bid >> 3);   // XCD swizzle (512 = 8*64)
    const int qt = flat & 31, bh = flat >> 5;
    const int q0 = qt * 128;

    const f16* kgb = kh_  + (size_t)bh * SEQ * DH;   // K' fragment-major
    const f16* vgb = vth_ + (size_t)bh * SEQ * DH;   // V' fragment-major

#define STAGE(s2, dbase)                                                      \
    do {                                                                      \
        gload_lds16(kgb + (size_t)(2 * (s2)) * 4096 + t * 8,                  \
                    smem + (dbase) + t * 16);                                 \
        gload_lds16(vgb + (size_t)(2 * (s2)) * 4096 + t * 8,                  \
                    smem + (dbase) + 8192 + t * 16);                          \
        gload_lds16(kgb + (size_t)(2 * (s2) + 1) * 4096 + t * 8,              \
                    smem + (dbase) + 16384 + t * 16);                         \
        gload_lds16(vgb + (size_t)(2 * (s2) + 1) * 4096 + t * 8,              \
                    smem + (dbase) + 24576 + t * 16);                         \
    } while (0)

    // Q fragments (B-operand): lane q=q31, k = h5*8 + ks*16 + j
    f16x8 qfh[4];
    {
        const int qrow = q0 + w4 * 32 + q31;
        size_t base = ((size_t)bh * SEQ + qrow) * DH + h5 * 8;
#pragma unroll
        for (int ks = 0; ks < 4; ++ks)
            qfh[ks] = *(const f16x8*)(qh_ + base + ks * 16);
    }

    f32x16 o_acc[2];
#pragma unroll
    for (int dt = 0; dt < 2; ++dt)
#pragma unroll
        for (int r = 0; r < 16; ++r) o_acc[dt][r] = 0.f;
    float run_l = 0.f;

    STAGE(0, 0);
    __syncthreads();

    const int NT = SEQ / 128;   // 32
    for (int s = 0; s < NT; ++s) {
        const int cur = s & 1;
        if (s + 1 < NT) STAGE(s + 1, (cur ^ 1) * 32768);
        const char* bK = smem + cur * 32768 + grp * 16384;
        const char* bV = bK + 8192;

        // --- S^T = K Q^T : conflict-free linear fragment reads
        f32x16 sacc[2];
        __builtin_amdgcn_s_setprio(1);
#pragma unroll
        for (int jb = 0; jb < 2; ++jb) {
            f32x16 a;
#pragma unroll
            for (int r = 0; r < 16; ++r) a[r] = 0.f;
#pragma unroll
            for (int ks = 0; ks < 4; ++ks) {
                f16x8 kf = *(const f16x8*)(bK + (jb * 4 + ks) * 1024 + lane * 16);
                a = __builtin_amdgcn_mfma_f32_32x32x16_f16(kf, qfh[ks], a, 0, 0, 0);
            }
            sacc[jb] = a;
        }
        __builtin_amdgcn_s_setprio(0);

        // --- P = exp2(S), pack to f16; row-sum via dot2 (consistent l)
        float ls0 = 0.f, ls1 = 0.f, ls2 = 0.f, ls3 = 0.f;
        unsigned pw[2][8];
#pragma unroll
        for (int jb = 0; jb < 2; ++jb)
#pragma unroll
            for (int k = 0; k < 8; ++k) {
                float p0 = exp2_raw(sacc[jb][2 * k]);
                float p1 = exp2_raw(sacc[jb][2 * k + 1]);
                pw[jb][k] = pk2(p0, p1);
                switch (k & 3) {
                    case 0: ls0 = dot2acc(pw[jb][k], ls0); break;
                    case 1: ls1 = dot2acc(pw[jb][k], ls1); break;
                    case 2: ls2 = dot2acc(pw[jb][k], ls2); break;
                    default: ls3 = dot2acc(pw[jb][k], ls3); break;
                }
            }
        float ls = (ls0 + ls1) + (ls2 + ls3);
        ls += __shfl_xor(ls, 32);
        run_l += ls;

        // --- O^T += Vt P^T : P B-frags via permlane32_swap; V' linear reads
        __builtin_amdgcn_s_setprio(1);
#pragma unroll
        for (int ks = 0; ks < 4; ++ks) {
            const int jb = ks >> 1, c = (ks & 1) * 4;
            unsigned y0a = pw[jb][c + 0];
            unsigned y0b = pw[jb][c + 1];
            unsigned y1a = pw[jb][c + 2];
            unsigned y1b = pw[jb][c + 3];
            pl32swap(y0a, y1a);   // y0a=B word0, y1a=B word2
            pl32swap(y0b, y1b);   // y0b=B word1, y1b=B word3
            union { f16x8 v; unsigned u[4]; } bb;
            bb.u[0] = y0a; bb.u[1] = y0b; bb.u[2] = y1a; bb.u[3] = y1b;
#pragma unroll
            for (int dt = 0; dt < 2; ++dt) {
                f16x8 vb = *(const f16x8*)(bV + (dt * 4 + ks) * 1024 + lane * 16);
                o_acc[dt] = __builtin_amdgcn_mfma_f32_32x32x16_f16(vb, bb.v, o_acc[dt], 0, 0, 0);
            }
        }
        __builtin_amdgcn_s_setprio(0);

        __syncthreads();   // drains prefetch + all LDS reads of buf[cur]
    }

    // --- merge B partials into A (plain sum: same exp2 base), epilogue by A
    if (grp == 1) {
        float* mb = (float*)(smem + w4 * 9216 + lane * 144);
#pragma unroll
        for (int dt = 0; dt < 2; ++dt)
#pragma unroll
            for (int rr = 0; rr < 4; ++rr) {
                float4 v4 = {o_acc[dt][rr*4+0], o_acc[dt][rr*4+1],
                             o_acc[dt][rr*4+2], o_acc[dt][rr*4+3]};
                *(float4*)(mb + dt * 16 + rr * 4) = v4;
            }
        mb[32] = run_l;
    }
    __syncthreads();
    if (grp == 0) {
        const float* mb = (const float*)(smem + wave * 9216 + lane * 144);
        float invl = 1.0f / (run_l + mb[32]);

        char* ep = smem + 36864 + wave * 4096;   // [32 q][64 d] f16, swizzled
#pragma unroll
        for (int dt = 0; dt < 2; ++dt)
#pragma unroll
            for (int rr = 0; rr < 4; ++rr) {
                float4 vB = *(const float4*)(mb + dt * 16 + rr * 4);
                f16x4 ov;
                ov[0] = (f16)((o_acc[dt][rr*4+0] + vB.x) * invl);
                ov[1] = (f16)((o_acc[dt][rr*4+1] + vB.y) * invl);
                ov[2] = (f16)((o_acc[dt][rr*4+2] + vB.z) * invl);
                ov[3] = (f16)((o_acc[dt][rr*4+3] + vB.w) * invl);
                int g = rr + 4 * dt;
                *(f16x4*)(ep + q31 * 128 + ((g ^ (q31 & 7)) * 16) + 8 * h5) = ov;
            }
        const int b_ = bh >> 3, hh = bh & 7;
#pragma unroll
        for (int itc = 0; itc < 4; ++itc) {
            int ch = lane + itc * 64;
            int row = ch >> 3, g = ch & 7;
            f16x8 v = *(const f16x8*)(ep + row * 128 + ((g ^ (row & 7)) * 16));
            int s = q0 + wave * 32 + row;
            *(f16x8*)(o_h + ((size_t)(b_ * SEQ + s)) * DIM + hh * DH + g * 8) = v;
        }
    }
#undef STAGE
}

// ---------------------------------------------------------------------------
// Kernel 3: output projection, 1-pass f16 MFMA + bias, BN=128, dbuf K-loop.
// ---------------------------------------------------------------------------
__global__ __launch_bounds__(256) void oproj_mfma_kernel(
    const f16* __restrict__ oh, const f16* __restrict__ wh,
    const float* __restrict__ bias, float* __restrict__ out)
{
    __shared__ __align__(16) char smem[49152];
    // dbuf d: d*24576 + {Oh 8K @0, Wh 16K @8192}
    const int t = threadIdx.x, lane = t & 63, wave = t >> 6;
    const int l15 = lane & 15, l4 = lane >> 4;
    const int m0 = blockIdx.x * 64;
    const int n0 = blockIdx.y * 128;

    const int r0 = t >> 3,         c0 = (t & 7) ^ (r0 & 7);
    const int r1 = (t + 256) >> 3, c1 = ((t + 256) & 7) ^ (r1 & 7);

#define STAGEO(k0, dbase)                                                     \
    do {                                                                      \
        gload_lds16(oh + (size_t)(m0 + r0) * DIM + (k0) + c0 * 8,             \
                    smem + (dbase) + t * 16);                                 \
        gload_lds16(oh + (size_t)(m0 + r1) * DIM + (k0) + c1 * 8,             \
                    smem + (dbase) + (t + 256) * 16);                         \
        _Pragma("unroll")                                                     \
        for (int it_ = 0; it_ < 4; ++it_) {                                   \
            int p_ = t + it_ * 256;                                           \
            int wr_ = p_ >> 3, wc_ = (p_ & 7) ^ (wr_ & 7);                    \
            gload_lds16(wh + (size_t)(n0 + wr_) * DIM + (k0) + wc_ * 8,       \
                        smem + (dbase) + 8192 + p_ * 16);                     \
        }                                                                     \
    } while (0)

    f32x4 acc[8];
#pragma unroll
    for (int nb = 0; nb < 8; ++nb) acc[nb] = (f32x4){0.f, 0.f, 0.f, 0.f};

    STAGEO(0, 0);
    __syncthreads();

    for (int ks = 0; ks < 8; ++ks) {
        const int cur = ks & 1;
        if (ks < 7) STAGEO((ks + 1) * 64, (cur ^ 1) * 24576);
        const char* bO = smem + cur * 24576;
        const char* bW = bO + 8192;

        f16x8 ah[2];
        const int arow = wave * 16 + l15;
#pragma unroll
        for (int kb = 0; kb < 2; ++kb) {
            int ac = (l4 + 4 * kb) ^ (arow & 7);
            ah[kb] = *(const f16x8*)(bO + arow * 128 + ac * 16);
        }
#pragma unroll
        for (int nb = 0; nb < 8; ++nb) {
            const int brow = nb * 16 + l15;
#pragma unroll
            for (int kb = 0; kb < 2; ++kb) {
                int bc = (l4 + 4 * kb) ^ (brow & 7);
                f16x8 b_h = *(const f16x8*)(bW + brow * 128 + bc * 16);
                acc[nb] = __builtin_amdgcn_mfma_f32_16x16x32_f16(ah[kb], b_h, acc[nb], 0, 0, 0);
            }
        }
        __syncthreads();
    }

#pragma unroll
    for (int nb = 0; nb < 8; ++nb) {
        int n = n0 + nb * 16 + l15;
        float bz = bias[n];
#pragma unroll
        for (int r = 0; r < 4; ++r) {
            int m = m0 + wave * 16 + l4 * 4 + r;
            out[(size_t)m * DIM + n] = acc[nb][r] + bz;
        }
    }
#undef STAGEO
}

// ---------------------------------------------------------------------------
extern "C" void kernel_launch(void* const* d_in, const int* in_sizes, int n_in,
                              void* d_out, int out_size, void* d_ws, size_t ws_size,
                              hipStream_t stream) {
    const float* x     = (const float*)d_in[0];
    const float* w_qkv = (const float*)d_in[1];
    const float* w_out = (const float*)d_in[2];
    const float* b_out = (const float*)d_in[3];
    float* out = (float*)d_out;

    const size_t per = (size_t)BATCH * HEADS * SEQ * DH;   // 4194304
    f16* base = (f16*)d_ws;
    f16* xh  = base;                 // 4194304
    f16* wqh = xh + per;             // 786432
    f16* woh = wqh + 786432;         // 262144
    f16* qh  = woh + 262144;
    f16* kh  = qh + per;
    f16* vth = kh + per;
    f16* o_h = vth + per;            // total ~44 MB

    prep_kernel<<<5120, 256, 0, stream>>>(x, w_qkv, w_out, xh, wqh, woh);
    qkv_mfma_kernel<<<dim3(128, 12), 256, 0, stream>>>(xh, wqh, qh, kh, vth);
    attn_mfma_kernel<<<512, 512, 0, stream>>>(qh, kh, vth, o_h);
    oproj_mfma_kernel<<<dim3(128, 4), 256, 0, stream>>>(o_h, woh, b_out, out);
}